// Round 8
// baseline (140.922 us; speedup 1.0000x reference)
//
#include <hip/hip_runtime.h>

#define TT 20
#define NSTK 1000
#define THREADS 256
#define NBLK 500

#define SC_SIG  1.44269504089f      // log2(e)
#define SC_TANH 2.88539008178f      // 2*log2(e)

typedef float f32x4 __attribute__((ext_vector_type(4)));
typedef _Float16 f16x8 __attribute__((ext_vector_type(8)));
typedef _Float16 f16x2 __attribute__((ext_vector_type(2)));

__device__ __forceinline__ float rcp_f(float x) { return __builtin_amdgcn_rcpf(x); }
__device__ __forceinline__ float exp2_f(float x) { return __builtin_amdgcn_exp2f(x); }

// A/B fragment k-convention: k = kf*32 + q*8 + j  (q = lane>>4, j = elem).
// Same bijection for A and B, so the true HW k-permutation cancels.
// A-frag LDS layout: [kf][q][row][j] shorts. kf 0,1 = x rows; kf 2,3 = h rows.
#define AIDX(kf, q, row, j) ((((kf) * 4 + (q)) * 16 + (row)) * 8 + (j))

extern "C" __global__ void __launch_bounds__(THREADS, 2)
lstm_att_f16(const float* __restrict__ x,
             const float* __restrict__ Wi, const float* __restrict__ bi,
             const float* __restrict__ Wo, const float* __restrict__ bo,
             const float* __restrict__ Wf, const float* __restrict__ bf_,
             const float* __restrict__ Wc, const float* __restrict__ bc,
             const float* __restrict__ Wt,
             float* __restrict__ out)
{
    __shared__ __align__(16) _Float16 afrag[2][2048];     // 8 KB  xh frags, double-buffered
    __shared__ __align__(16) _Float16 hhist[TT * 8 * 64]; // 20 KB h history

    const int tid  = threadIdx.x;
    const int lane = tid & 63;
    const int w    = tid >> 6;            // wave 0..3
    const int q    = lane >> 4;           // k-subgroup
    const int r16  = lane & 15;           // A row / B col within frag
    const int dcol = w * 16 + r16;        // this lane's d column (0..63)
    const bool hi  = lane >= 32;
    const int rowbase = ((lane & 31) >> 4) * 4 + (hi ? 2 : 0);  // this lane's 2 batch rows

    const float* Wg[4] = {Wi, Wo, Wf, Wc};
    const float* Bg[4] = {bi, bo, bf_, bc};

    // ---- prefetch registers: stock weights stream here while previous stock computes ----
    float wraw[4][4][8];                  // 128 VGPRs
    float braw[4];

    // issue loads for stock n0 = 2*blockIdx.x (scalar strided: full-MLP, 64B-efficient)
    {
        const int n0 = blockIdx.x * 2;
        #pragma unroll
        for (int g = 0; g < 4; ++g) {
            const float* base = Wg[g] + (size_t)n0 * 8192 + dcol;
            #pragma unroll
            for (int kf = 0; kf < 4; ++kf)
                #pragma unroll
                for (int j = 0; j < 8; ++j)
                    wraw[g][kf][j] = base[(kf * 32 + q * 8 + j) * 64];
            braw[g] = Bg[g][n0 * 64 + dcol];
        }
    }

    // invariant addressing (independent of stock)
    const int sb = tid >> 5, dx = (tid & 31) * 2;
    const int sbase = AIDX(dx >> 5, (dx & 31) >> 3, sb, dx & 7);
    const int kfh = 2 + (dcol >> 5), kkh = dcol & 31;
    const int hb0 = AIDX(kfh, kkh >> 3, rowbase, kkh & 7);

    f16x8 bw[4][4];                       // log2e-prescaled f16 B-frags
    float biasv[4];

    for (int ss = 0; ss < 2; ++ss) {
        const int n = blockIdx.x * 2 + ss;

        // ---- convert arrived weights -> f16 frags (waits vmcnt as needed) ----
        #pragma unroll
        for (int g = 0; g < 4; ++g) {
            const float sc = (g == 3) ? SC_TANH : SC_SIG;
            #pragma unroll
            for (int kf = 0; kf < 4; ++kf)
                #pragma unroll
                for (int j = 0; j < 8; ++j)
                    bw[g][kf][j] = (_Float16)(wraw[g][kf][j] * sc);
            biasv[g] = braw[g] * sc;
        }

        // ---- issue next stock's weight loads; they stream during the loop below ----
        if (ss == 0) {
            const int n1 = blockIdx.x * 2 + 1;
            #pragma unroll
            for (int g = 0; g < 4; ++g) {
                const float* base = Wg[g] + (size_t)n1 * 8192 + dcol;
                #pragma unroll
                for (int kf = 0; kf < 4; ++kf)
                    #pragma unroll
                    for (int j = 0; j < 8; ++j)
                        wraw[g][kf][j] = base[(kf * 32 + q * 8 + j) * 64];
                braw[g] = Bg[g][n1 * 64 + dcol];
            }
        }

        // ---- per-stock init: stage x(t=0), zero h rows of buf0, prefetch x(t=1) ----
        const float* xptr = x + ((size_t)sb * TT * NSTK + (size_t)n) * 64 + dx;
        {
            const float2 x0 = *(const float2*)xptr;
            *(f16x2*)(&afrag[0][sbase]) = (f16x2){(_Float16)x0.x, (_Float16)x0.y};
        }
        #pragma unroll
        for (int u = 0; u < 4; ++u)
            afrag[0][1024 + tid + u * THREADS] = (_Float16)0.0f;
        float2 xreg = *(const float2*)(xptr + (size_t)NSTK * 64);

        float cst0 = 0.f, cst1 = 0.f;
        __syncthreads();    // staging + zeroing visible; also orders vs prev stock's tail reads

        for (int t = 0; t < TT; ++t) {
            const int cur = t & 1, nxt = cur ^ 1;

            f16x8 af[4];
            #pragma unroll
            for (int kf = 0; kf < 4; ++kf)
                af[kf] = *(const f16x8*)(&afrag[cur][AIDX(kf, q, r16, 0)]);

            if (t + 1 < TT)
                *(f16x2*)(&afrag[nxt][sbase]) = (f16x2){(_Float16)xreg.x, (_Float16)xreg.y};
            {
                const int tn = (t + 2 < TT) ? t + 2 : TT - 1;
                xreg = *(const float2*)(xptr + (size_t)tn * NSTK * 64);
            }

            f32x4 acc[4];
            #pragma unroll
            for (int g = 0; g < 4; ++g)
                acc[g] = (f32x4){biasv[g], biasv[g], biasv[g], biasv[g]};
            #pragma unroll
            for (int kf = 0; kf < 4; ++kf) {
                #pragma unroll
                for (int g = 0; g < 4; ++g)
                    acc[g] = __builtin_amdgcn_mfma_f32_16x16x32_f16(af[kf], bw[g][kf], acc[g], 0, 0, 0);
            }

            // ship C rows 2,3 to partner lane (+32); every lane then handles 2 rows
            float p0[4], p1[4];
            #pragma unroll
            for (int g = 0; g < 4; ++g) {
                const float t2 = __shfl_xor(acc[g][2], 32, 64);
                const float t3 = __shfl_xor(acc[g][3], 32, 64);
                p0[g] = hi ? t2 : acc[g][0];
                p1[g] = hi ? t3 : acc[g][1];
            }

            // gates via raw v_exp_f32 (log2e folded into weights/bias)
            const float ig0 = rcp_f(1.0f + exp2_f(-p0[0]));
            const float og0 = rcp_f(1.0f + exp2_f(-p0[1]));
            const float fg0 = rcp_f(1.0f + exp2_f(-p0[2]));
            const float cg0 = 1.0f - 2.0f * rcp_f(exp2_f(p0[3]) + 1.0f);
            const float ig1 = rcp_f(1.0f + exp2_f(-p1[0]));
            const float og1 = rcp_f(1.0f + exp2_f(-p1[1]));
            const float fg1 = rcp_f(1.0f + exp2_f(-p1[2]));
            const float cg1 = 1.0f - 2.0f * rcp_f(exp2_f(p1[3]) + 1.0f);
            cst0 = fmaf(fg0, cst0, ig0 * cg0);
            cst1 = fmaf(fg1, cst1, ig1 * cg1);
            const float th0 = 1.0f - 2.0f * rcp_f(exp2_f(cst0 * SC_TANH) + 1.0f);
            const float th1 = 1.0f - 2.0f * rcp_f(exp2_f(cst1 * SC_TANH) + 1.0f);
            const float h0 = og0 * th0;
            const float h1 = og1 * th1;

            afrag[nxt][hb0]     = (_Float16)h0;
            afrag[nxt][hb0 + 8] = (_Float16)h1;
            hhist[(t * 8 + rowbase) * 64 + dcol]     = (_Float16)h0;
            hhist[(t * 8 + rowbase + 1) * 64 + dcol] = (_Float16)h1;

            __syncthreads();   // publishes x(t+1)+h(t) in buf[nxt]; closes reads of buf[cur]
        }

        // ---- deferred attention: wave w handles batches 2w, 2w+1 ----
        const float* wtg = Wt + (size_t)n * (TT * 64);
        #pragma unroll
        for (int bb = 0; bb < 2; ++bb) {
            const int b = 2 * w + bb;
            float s[TT];
            #pragma unroll
            for (int t = 0; t < TT; ++t)
                s[t] = (float)hhist[(t * 8 + b) * 64 + lane] * wtg[t * 64 + lane];
            #pragma unroll
            for (int t = 0; t < TT; ++t) {
                #pragma unroll
                for (int mk = 32; mk >= 1; mk >>= 1)
                    s[t] += __shfl_xor(s[t], mk, 64);
            }
            float m = s[0];
            #pragma unroll
            for (int t = 1; t < TT; ++t) m = fmaxf(m, s[t]);
            float se = 0.f;
            #pragma unroll
            for (int t = 0; t < TT; ++t) { s[t] = exp2_f((s[t] - m) * SC_SIG); se += s[t]; }
            const float rs = rcp_f(se);
            float o = 0.f;
            #pragma unroll
            for (int t = 0; t < TT; ++t)
                o = fmaf(s[t], (float)hhist[(t * 8 + b) * 64 + lane], o);
            out[((size_t)b * NSTK + n) * 64 + lane] = o * rs;
        }
    }
}

extern "C" void kernel_launch(void* const* d_in, const int* in_sizes, int n_in,
                              void* d_out, int out_size, void* d_ws, size_t ws_size,
                              hipStream_t stream) {
    const float* x  = (const float*)d_in[0];
    const float* Wi = (const float*)d_in[1];
    const float* bi = (const float*)d_in[2];
    const float* Wo = (const float*)d_in[3];
    const float* bo = (const float*)d_in[4];
    const float* Wf = (const float*)d_in[5];
    const float* bf = (const float*)d_in[6];
    const float* Wc = (const float*)d_in[7];
    const float* bc = (const float*)d_in[8];
    const float* Wt = (const float*)d_in[9];
    float* out = (float*)d_out;

    lstm_att_f16<<<NBLK, THREADS, 0, stream>>>(
        x, Wi, bi, Wo, bo, Wf, bf, Wc, bc, Wt, out);
}

// Round 9
// 85.101 us; speedup vs baseline: 1.6559x; 1.6559x over previous
//
#include <hip/hip_runtime.h>

#define TT 20
#define NSTK 1000
#define SC_SIG  1.44269504089f      // log2(e)
#define SC_TANH 2.88539008178f      // 2*log2(e)
#define HPAD 72                     // 144B row stride: h-frag b128 reads <=4-way bank alias

typedef float f32x4 __attribute__((ext_vector_type(4)));
typedef _Float16 f16x8 __attribute__((ext_vector_type(8)));

__device__ __forceinline__ float rcp_f(float x) { return __builtin_amdgcn_rcpf(x); }
__device__ __forceinline__ float exp2_f(float x) { return __builtin_amdgcn_exp2f(x); }

// A/B fragment k-convention: k = kf*32 + q*8 + j  (q = lane>>4, j = elem).
// Same bijection for A and B, so the true HW k-permutation cancels.
// A rows = batch (0..7 valid; rows 8..15 are duplicates of 0..7 via bsrc clamp,
// producing C rows 8..15 which are discarded). C: col = lane&15, row = (lane>>4)*4+reg.

extern "C" __global__ void __launch_bounds__(64, 1)
lstm_1wave(const float* __restrict__ x,
           const float* __restrict__ Wi, const float* __restrict__ bi,
           const float* __restrict__ Wo, const float* __restrict__ bo,
           const float* __restrict__ Wf, const float* __restrict__ bf_,
           const float* __restrict__ Wc, const float* __restrict__ bc,
           const float* __restrict__ Wt,
           float* __restrict__ out)
{
    // hh[t+1] = h(t); hh[0] = zeros. Doubles as attention history. 24.2 KB.
    __shared__ __align__(16) _Float16 hh[TT + 1][8][HPAD];

    const int lane = threadIdx.x;        // single wave: 0..63
    const int q    = lane >> 4;          // k-subgroup
    const int r16  = lane & 15;          // A row / B col / C col
    const int bsrc = r16 & 7;            // batch whose xh this lane stages (rows 8-15 dup)
    const bool hi  = lane >= 32;
    const int rb   = ((lane & 31) >> 4) * 4 + (hi ? 2 : 0);   // epilogue rows rb, rb+1
    const int n    = blockIdx.x;

    // zero hh[0] (8*72 f16 = 288 dwords)
    for (int i = lane; i < 288; i += 64) ((unsigned*)hh)[i] = 0u;

    const float* Wg[4] = {Wi, Wo, Wf, Wc};
    const float* Bg[4] = {bi, bo, bf_, bc};

    // bias for C cols (log2e-folded)
    float biasv[4][4];                   // [g][cg]
    #pragma unroll
    for (int g = 0; g < 4; ++g) {
        const float sc = (g == 3) ? SC_TANH : SC_SIG;
        #pragma unroll
        for (int cg = 0; cg < 4; ++cg)
            biasv[g][cg] = Bg[g][n * 64 + cg * 16 + r16] * sc;
    }

    // persistent weights: all 4 gates, full K=128, full d=64 -> 256 VGPRs of f16 frags
    f16x8 bw[4][4][4];                   // [g][kf][cg]
    #pragma unroll
    for (int g = 0; g < 4; ++g) {
        const float* base = Wg[g] + (size_t)n * 8192 + r16;
        const float sc = (g == 3) ? SC_TANH : SC_SIG;
        float tmp[4][4][8];
        #pragma unroll
        for (int kf = 0; kf < 4; ++kf)
            #pragma unroll
            for (int cg = 0; cg < 4; ++cg)
                #pragma unroll
                for (int j = 0; j < 8; ++j)
                    tmp[kf][cg][j] = base[(kf * 32 + q * 8 + j) * 64 + cg * 16];
        #pragma unroll
        for (int kf = 0; kf < 4; ++kf)
            #pragma unroll
            for (int cg = 0; cg < 4; ++cg)
                #pragma unroll
                for (int j = 0; j < 8; ++j)
                    bw[g][kf][cg][j] = (_Float16)(tmp[kf][cg][j] * sc);
    }

    // x prefetch (t=0): lane covers din q*8..q*8+7 and 32+q*8..+7 for batch bsrc
    const float* xq = x + ((size_t)(bsrc * TT) * NSTK + n) * 64 + q * 8;
    float4 xp0 = *(const float4*)(xq);
    float4 xp1 = *(const float4*)(xq + 4);
    float4 xp2 = *(const float4*)(xq + 32);
    float4 xp3 = *(const float4*)(xq + 36);

    float cst0[4] = {0.f, 0.f, 0.f, 0.f};
    float cst1[4] = {0.f, 0.f, 0.f, 0.f};

    for (int t = 0; t < TT; ++t) {
        __syncthreads();   // 1-wave barrier: orders prev-step ds_writes vs this step's reads

        f16x8 af[4];
        af[2] = *(const f16x8*)&hh[t][bsrc][q * 8];
        af[3] = *(const f16x8*)&hh[t][bsrc][32 + q * 8];
        #pragma unroll
        for (int j = 0; j < 4; ++j) {
            af[0][j]     = (_Float16)(&xp0.x)[j];
            af[0][4 + j] = (_Float16)(&xp1.x)[j];
            af[1][j]     = (_Float16)(&xp2.x)[j];
            af[1][4 + j] = (_Float16)(&xp3.x)[j];
        }

        // prefetch x(t+1): ~full step of latency cover
        {
            const size_t off = (size_t)((t + 1 < TT) ? t + 1 : t) * (NSTK * 64);
            xp0 = *(const float4*)(xq + off);
            xp1 = *(const float4*)(xq + off + 4);
            xp2 = *(const float4*)(xq + off + 32);
            xp3 = *(const float4*)(xq + off + 36);
        }

        f32x4 acc[4][4];                 // [g][cg]
        #pragma unroll
        for (int g = 0; g < 4; ++g)
            #pragma unroll
            for (int cg = 0; cg < 4; ++cg)
                acc[g][cg] = (f32x4){biasv[g][cg], biasv[g][cg], biasv[g][cg], biasv[g][cg]};

        #pragma unroll
        for (int kf = 0; kf < 4; ++kf)
            #pragma unroll
            for (int g = 0; g < 4; ++g)
                #pragma unroll
                for (int cg = 0; cg < 4; ++cg)
                    acc[g][cg] = __builtin_amdgcn_mfma_f32_16x16x32_f16(
                        af[kf], bw[g][kf][cg], acc[g][cg], 0, 0, 0);

        // ship C rows 2,3 to partner lane (+32); every lane then owns rows rb, rb+1
        float p0[4][4], p1[4][4];
        #pragma unroll
        for (int g = 0; g < 4; ++g)
            #pragma unroll
            for (int cg = 0; cg < 4; ++cg) {
                const float u2 = __shfl_xor(acc[g][cg][2], 32, 64);
                const float u3 = __shfl_xor(acc[g][cg][3], 32, 64);
                p0[g][cg] = hi ? u2 : acc[g][cg][0];
                p1[g][cg] = hi ? u3 : acc[g][cg][1];
            }

        // gates via raw v_exp_f32 (log2e folded); 2 rows x 4 d per lane
        #pragma unroll
        for (int cg = 0; cg < 4; ++cg) {
            const float ig0 = rcp_f(1.0f + exp2_f(-p0[0][cg]));
            const float og0 = rcp_f(1.0f + exp2_f(-p0[1][cg]));
            const float fg0 = rcp_f(1.0f + exp2_f(-p0[2][cg]));
            const float cg0 = 1.0f - 2.0f * rcp_f(exp2_f(p0[3][cg]) + 1.0f);
            const float ig1 = rcp_f(1.0f + exp2_f(-p1[0][cg]));
            const float og1 = rcp_f(1.0f + exp2_f(-p1[1][cg]));
            const float fg1 = rcp_f(1.0f + exp2_f(-p1[2][cg]));
            const float cg1 = 1.0f - 2.0f * rcp_f(exp2_f(p1[3][cg]) + 1.0f);
            cst0[cg] = fmaf(fg0, cst0[cg], ig0 * cg0);
            cst1[cg] = fmaf(fg1, cst1[cg], ig1 * cg1);
            const float h0 = og0 * (1.0f - 2.0f * rcp_f(exp2_f(cst0[cg] * SC_TANH) + 1.0f));
            const float h1 = og1 * (1.0f - 2.0f * rcp_f(exp2_f(cst1[cg] * SC_TANH) + 1.0f));
            hh[t + 1][rb][cg * 16 + r16]     = (_Float16)h0;   // banks 2-way: free
            hh[t + 1][rb + 1][cg * 16 + r16] = (_Float16)h1;
        }
    }

    __syncthreads();

    // ---- attention tail: all 8 batches, one wave ----
    const float* wtg = Wt + (size_t)n * (TT * 64) + lane;
    float wtv[TT];
    #pragma unroll
    for (int t = 0; t < TT; ++t) wtv[t] = wtg[t * 64];

    for (int b = 0; b < 8; ++b) {
        float s[TT];
        #pragma unroll
        for (int t = 0; t < TT; ++t)
            s[t] = (float)hh[t + 1][b][lane] * wtv[t];
        #pragma unroll
        for (int t = 0; t < TT; ++t) {
            #pragma unroll
            for (int mk = 32; mk >= 1; mk >>= 1)
                s[t] += __shfl_xor(s[t], mk, 64);
        }
        float m = s[0];
        #pragma unroll
        for (int t = 1; t < TT; ++t) m = fmaxf(m, s[t]);
        float se = 0.f;
        #pragma unroll
        for (int t = 0; t < TT; ++t) { s[t] = exp2_f((s[t] - m) * SC_SIG); se += s[t]; }
        const float rs = rcp_f(se);
        float o = 0.f;
        #pragma unroll
        for (int t = 0; t < TT; ++t)
            o = fmaf(s[t], (float)hh[t + 1][b][lane], o);
        out[((size_t)b * NSTK + n) * 64 + lane] = o * rs;
    }
}

extern "C" void kernel_launch(void* const* d_in, const int* in_sizes, int n_in,
                              void* d_out, int out_size, void* d_ws, size_t ws_size,
                              hipStream_t stream) {
    const float* x  = (const float*)d_in[0];
    const float* Wi = (const float*)d_in[1];
    const float* bi = (const float*)d_in[2];
    const float* Wo = (const float*)d_in[3];
    const float* bo = (const float*)d_in[4];
    const float* Wf = (const float*)d_in[5];
    const float* bf = (const float*)d_in[6];
    const float* Wc = (const float*)d_in[7];
    const float* bc = (const float*)d_in[8];
    const float* Wt = (const float*)d_in[9];
    float* out = (float*)d_out;

    lstm_1wave<<<NSTK, 64, 0, stream>>>(
        x, Wi, bi, Wo, bo, Wf, bf, Wc, bc, Wt, out);
}

// Round 10
// 60.968 us; speedup vs baseline: 2.3114x; 1.3958x over previous
//
#include <hip/hip_runtime.h>

#define TT 20
#define NSTK 1000
#define THREADS 256
#define NBLK 500

#define SC_SIG  1.44269504089f      // log2(e)
#define SC_TANH 2.88539008178f      // 2*log2(e)

typedef float f32x4 __attribute__((ext_vector_type(4)));
typedef _Float16 f16x8 __attribute__((ext_vector_type(8)));
typedef _Float16 f16x2 __attribute__((ext_vector_type(2)));

__device__ __forceinline__ float rcp_f(float x) { return __builtin_amdgcn_rcpf(x); }
__device__ __forceinline__ float exp2_f(float x) { return __builtin_amdgcn_exp2f(x); }

// A/B fragment k-convention: k = kf*32 + q*8 + j  (q = lane>>4, j = elem).
// Same bijection for A and B, so the true HW k-permutation cancels.
// A-frag LDS layout: [kf][q][row][j] shorts. kf 0,1 = x rows; kf 2,3 = h rows.
#define AIDX(kf, q, row, j) ((((kf) * 4 + (q)) * 16 + (row)) * 8 + (j))

extern "C" __global__ void __launch_bounds__(THREADS, 2)
lstm_att_2stk(const float* __restrict__ x,
              const float* __restrict__ Wi, const float* __restrict__ bi,
              const float* __restrict__ Wo, const float* __restrict__ bo,
              const float* __restrict__ Wf, const float* __restrict__ bf_,
              const float* __restrict__ Wc, const float* __restrict__ bc,
              const float* __restrict__ Wt,
              float* __restrict__ out)
{
    __shared__ __align__(16) _Float16 afragA[2][2048];     // 8 KB
    __shared__ __align__(16) _Float16 afragB[2][2048];     // 8 KB
    __shared__ __align__(16) _Float16 hhistA[TT * 8 * 64]; // 20 KB
    __shared__ __align__(16) _Float16 hhistB[TT * 8 * 64]; // 20 KB

    const int n0   = blockIdx.x * 2;      // stock A; stock B = n0+1
    const int tid  = threadIdx.x;
    const int lane = tid & 63;
    const int w    = tid >> 6;            // wave 0..3
    const int q    = lane >> 4;           // k-subgroup
    const int r16  = lane & 15;           // A row / B col within frag
    const int dcol = w * 16 + r16;        // this lane's d column (0..63)
    const bool hi  = lane >= 32;
    const int rowbase = ((lane & 31) >> 4) * 4 + (hi ? 2 : 0);  // this lane's 2 batch rows

    // ---- persistent weight B-frags for BOTH stocks, strided scalar loads (R4 pattern) ----
    f16x8 bwA[4][4], bwB[4][4];           // log2e-prescaled f16
    float biasA[4], biasB[4];
    {
        const float* Wg[4] = {Wi, Wo, Wf, Wc};
        const float* Bg[4] = {bi, bo, bf_, bc};
        #pragma unroll
        for (int g = 0; g < 4; ++g) {
            const float sc = (g == 3) ? SC_TANH : SC_SIG;
            const float* baseA = Wg[g] + (size_t)n0 * 8192 + dcol;
            const float* baseB = baseA + 8192;
            #pragma unroll
            for (int kf = 0; kf < 4; ++kf)
                #pragma unroll
                for (int j = 0; j < 8; ++j) {
                    const int off = (kf * 32 + q * 8 + j) * 64;
                    bwA[g][kf][j] = (_Float16)(baseA[off] * sc);
                    bwB[g][kf][j] = (_Float16)(baseB[off] * sc);
                }
            biasA[g] = Bg[g][n0 * 64 + dcol] * sc;
            biasB[g] = Bg[g][(n0 + 1) * 64 + dcol] * sc;
        }
    }

    // ---- x staging role: thread -> (batch sb, dims dx,dx+1) ----
    const int sb = tid >> 5, dx = (tid & 31) * 2;
    const int sbase = AIDX(dx >> 5, (dx & 31) >> 3, sb, dx & 7);
    const float* xptrA = x + ((size_t)sb * TT * NSTK + n0) * 64 + dx;
    const float* xptrB = xptrA + 64;      // n0+1

    // init: stage x(t=0) into buf0 of both stocks; zero h rows of both buf0
    {
        const float2 a0 = *(const float2*)xptrA;
        const float2 b0 = *(const float2*)xptrB;
        *(f16x2*)(&afragA[0][sbase]) = (f16x2){(_Float16)a0.x, (_Float16)a0.y};
        *(f16x2*)(&afragB[0][sbase]) = (f16x2){(_Float16)b0.x, (_Float16)b0.y};
    }
    #pragma unroll
    for (int u = 0; u < 4; ++u) {
        afragA[0][1024 + tid + u * THREADS] = (_Float16)0.0f;
        afragB[0][1024 + tid + u * THREADS] = (_Float16)0.0f;
    }
    float2 xregA = *(const float2*)(xptrA + (size_t)NSTK * 64);   // prefetch t=1
    float2 xregB = *(const float2*)(xptrB + (size_t)NSTK * 64);

    float cA0 = 0.f, cA1 = 0.f, cB0 = 0.f, cB1 = 0.f;

    __syncthreads();

    const int kfh = 2 + (dcol >> 5), kkh = dcol & 31;
    const int hb0 = AIDX(kfh, kkh >> 3, rowbase, kkh & 7);

    for (int t = 0; t < TT; ++t) {
        const int cur = t & 1, nxt = cur ^ 1;

        // A-frag reads from current buffers (both stocks)
        f16x8 afA[4], afB[4];
        #pragma unroll
        for (int kf = 0; kf < 4; ++kf) {
            afA[kf] = *(const f16x8*)(&afragA[cur][AIDX(kf, q, r16, 0)]);
            afB[kf] = *(const f16x8*)(&afragB[cur][AIDX(kf, q, r16, 0)]);
        }

        // stage x(t+1) into next buffers; prefetch t+2 (hidden under MFMA)
        if (t + 1 < TT) {
            *(f16x2*)(&afragA[nxt][sbase]) = (f16x2){(_Float16)xregA.x, (_Float16)xregA.y};
            *(f16x2*)(&afragB[nxt][sbase]) = (f16x2){(_Float16)xregB.x, (_Float16)xregB.y};
        }
        {
            const size_t off = (size_t)((t + 2 < TT) ? t + 2 : TT - 1) * (NSTK * 64);
            xregA = *(const float2*)(xptrA + off);
            xregB = *(const float2*)(xptrB + off);
        }

        // MFMA: 16 per stock, independent chains
        f32x4 accA[4], accB[4];
        #pragma unroll
        for (int g = 0; g < 4; ++g) {
            accA[g] = (f32x4){biasA[g], biasA[g], biasA[g], biasA[g]};
            accB[g] = (f32x4){biasB[g], biasB[g], biasB[g], biasB[g]};
        }
        #pragma unroll
        for (int kf = 0; kf < 4; ++kf) {
            #pragma unroll
            for (int g = 0; g < 4; ++g) {
                accA[g] = __builtin_amdgcn_mfma_f32_16x16x32_f16(afA[kf], bwA[g][kf], accA[g], 0, 0, 0);
                accB[g] = __builtin_amdgcn_mfma_f32_16x16x32_f16(afB[kf], bwB[g][kf], accB[g], 0, 0, 0);
            }
        }

        // ship C rows 2,3 to partner lane (+32); every lane then handles 2 rows per stock
        float pA0[4], pA1[4], pB0[4], pB1[4];
        #pragma unroll
        for (int g = 0; g < 4; ++g) {
            const float a2 = __shfl_xor(accA[g][2], 32, 64);
            const float a3 = __shfl_xor(accA[g][3], 32, 64);
            const float b2 = __shfl_xor(accB[g][2], 32, 64);
            const float b3 = __shfl_xor(accB[g][3], 32, 64);
            pA0[g] = hi ? a2 : accA[g][0];
            pA1[g] = hi ? a3 : accA[g][1];
            pB0[g] = hi ? b2 : accB[g][0];
            pB1[g] = hi ? b3 : accB[g][1];
        }

        // gates via raw v_exp_f32 (log2e folded); 4 independent chains
        const float igA0 = rcp_f(1.0f + exp2_f(-pA0[0]));
        const float ogA0 = rcp_f(1.0f + exp2_f(-pA0[1]));
        const float fgA0 = rcp_f(1.0f + exp2_f(-pA0[2]));
        const float cgA0 = 1.0f - 2.0f * rcp_f(exp2_f(pA0[3]) + 1.0f);
        const float igA1 = rcp_f(1.0f + exp2_f(-pA1[0]));
        const float ogA1 = rcp_f(1.0f + exp2_f(-pA1[1]));
        const float fgA1 = rcp_f(1.0f + exp2_f(-pA1[2]));
        const float cgA1 = 1.0f - 2.0f * rcp_f(exp2_f(pA1[3]) + 1.0f);
        const float igB0 = rcp_f(1.0f + exp2_f(-pB0[0]));
        const float ogB0 = rcp_f(1.0f + exp2_f(-pB0[1]));
        const float fgB0 = rcp_f(1.0f + exp2_f(-pB0[2]));
        const float cgB0 = 1.0f - 2.0f * rcp_f(exp2_f(pB0[3]) + 1.0f);
        const float igB1 = rcp_f(1.0f + exp2_f(-pB1[0]));
        const float ogB1 = rcp_f(1.0f + exp2_f(-pB1[1]));
        const float fgB1 = rcp_f(1.0f + exp2_f(-pB1[2]));
        const float cgB1 = 1.0f - 2.0f * rcp_f(exp2_f(pB1[3]) + 1.0f);

        cA0 = fmaf(fgA0, cA0, igA0 * cgA0);
        cA1 = fmaf(fgA1, cA1, igA1 * cgA1);
        cB0 = fmaf(fgB0, cB0, igB0 * cgB0);
        cB1 = fmaf(fgB1, cB1, igB1 * cgB1);
        const float hA0 = ogA0 * (1.0f - 2.0f * rcp_f(exp2_f(cA0 * SC_TANH) + 1.0f));
        const float hA1 = ogA1 * (1.0f - 2.0f * rcp_f(exp2_f(cA1 * SC_TANH) + 1.0f));
        const float hB0 = ogB0 * (1.0f - 2.0f * rcp_f(exp2_f(cB0 * SC_TANH) + 1.0f));
        const float hB1 = ogB1 * (1.0f - 2.0f * rcp_f(exp2_f(cB1 * SC_TANH) + 1.0f));

        // h -> next buffers' A-frags + histories
        afragA[nxt][hb0]     = (_Float16)hA0;
        afragA[nxt][hb0 + 8] = (_Float16)hA1;
        afragB[nxt][hb0]     = (_Float16)hB0;
        afragB[nxt][hb0 + 8] = (_Float16)hB1;
        hhistA[(t * 8 + rowbase) * 64 + dcol]     = (_Float16)hA0;
        hhistA[(t * 8 + rowbase + 1) * 64 + dcol] = (_Float16)hA1;
        hhistB[(t * 8 + rowbase) * 64 + dcol]     = (_Float16)hB0;
        hhistB[(t * 8 + rowbase + 1) * 64 + dcol] = (_Float16)hB1;

        __syncthreads();   // publishes x(t+1)+h(t) in buf[nxt]; closes reads of buf[cur]
    }

    // ---- deferred attention: wave w handles batches 2w, 2w+1 for both stocks ----
    const float* wtgA = Wt + (size_t)n0 * (TT * 64);
    const float* wtgB = wtgA + TT * 64;
    #pragma unroll
    for (int bb = 0; bb < 2; ++bb) {
        const int b = 2 * w + bb;
        float sA[TT], sB[TT];
        #pragma unroll
        for (int t = 0; t < TT; ++t) {
            sA[t] = (float)hhistA[(t * 8 + b) * 64 + lane] * wtgA[t * 64 + lane];
            sB[t] = (float)hhistB[(t * 8 + b) * 64 + lane] * wtgB[t * 64 + lane];
        }
        #pragma unroll
        for (int t = 0; t < TT; ++t) {
            #pragma unroll
            for (int mk = 32; mk >= 1; mk >>= 1) {
                sA[t] += __shfl_xor(sA[t], mk, 64);
                sB[t] += __shfl_xor(sB[t], mk, 64);
            }
        }
        float mA = sA[0], mB = sB[0];
        #pragma unroll
        for (int t = 1; t < TT; ++t) { mA = fmaxf(mA, sA[t]); mB = fmaxf(mB, sB[t]); }
        float seA = 0.f, seB = 0.f;
        #pragma unroll
        for (int t = 0; t < TT; ++t) {
            sA[t] = exp2_f((sA[t] - mA) * SC_SIG); seA += sA[t];
            sB[t] = exp2_f((sB[t] - mB) * SC_SIG); seB += sB[t];
        }
        const float rsA = rcp_f(seA), rsB = rcp_f(seB);
        float oA = 0.f, oB = 0.f;
        #pragma unroll
        for (int t = 0; t < TT; ++t) {
            oA = fmaf(sA[t], (float)hhistA[(t * 8 + b) * 64 + lane], oA);
            oB = fmaf(sB[t], (float)hhistB[(t * 8 + b) * 64 + lane], oB);
        }
        out[((size_t)b * NSTK + n0) * 64 + lane]     = oA * rsA;
        out[((size_t)b * NSTK + n0 + 1) * 64 + lane] = oB * rsB;
    }
}

extern "C" void kernel_launch(void* const* d_in, const int* in_sizes, int n_in,
                              void* d_out, int out_size, void* d_ws, size_t ws_size,
                              hipStream_t stream) {
    const float* x  = (const float*)d_in[0];
    const float* Wi = (const float*)d_in[1];
    const float* bi = (const float*)d_in[2];
    const float* Wo = (const float*)d_in[3];
    const float* bo = (const float*)d_in[4];
    const float* Wf = (const float*)d_in[5];
    const float* bf = (const float*)d_in[6];
    const float* Wc = (const float*)d_in[7];
    const float* bc = (const float*)d_in[8];
    const float* Wt = (const float*)d_in[9];
    float* out = (float*)d_out;

    lstm_att_2stk<<<NBLK, THREADS, 0, stream>>>(
        x, Wi, bi, Wo, bo, Wf, bf, Wc, bc, Wt, out);
}